// Round 3
// baseline (302.069 us; speedup 1.0000x reference)
//
#include <hip/hip_runtime.h>
#include <math.h>

// SpectralTokenizer: 262144 rows x 100 fp32 -> per row 5 frames (hop 8, len 64),
// Hann window, rfft-64, log1p(|.|), freq-major flatten -> 165 fp32 per row.
//
// R1: VGPR_Count=56 with 64 live floats/thread -> AGPR spill shuffling, VALU
//     inflated ~3x (158K busy-cyc/SIMD vs ~55K hand count), dur ~105us.
// R2: __launch_bounds__(320,2) did not move it (bench 271->267us).
// R3: structural fix — split each frame's FFT-32 across TWO lanes (lane^1
//     pair). 16 complex per lane (~50 VGPRs live), stage 5 + rfft recon
//     exchange one complex per step via __shfl_xor. Native sqrt. 640-thread
//     blocks -> 30 waves/CU at same 42.2KB LDS.

#define ROWS_PER_BLOCK 64
#define BLOCK_THREADS (ROWS_PER_BLOCK * 5 * 2)   // 640 = 10 waves
#define ROW_LEN 100
#define OUT_PER_ROW 165                          // 33 freq * 5 frames

// cos/sin(2*pi*j/32), j=0..15  (FFT-32 twiddles, e^{-2pi i j/32} = c - i*s)
constexpr float W32C[16] = {
    1.0f, 0.980785280403230f, 0.923879532511287f, 0.831469612302545f,
    0.707106781186548f, 0.555570233019602f, 0.382683432365090f, 0.195090322016128f,
    0.0f, -0.195090322016128f, -0.382683432365090f, -0.555570233019602f,
    -0.707106781186548f, -0.831469612302545f, -0.923879532511287f, -0.980785280403230f};
constexpr float W32S[16] = {
    0.0f, 0.195090322016128f, 0.382683432365090f, 0.555570233019602f,
    0.707106781186548f, 0.831469612302545f, 0.923879532511287f, 0.980785280403230f,
    1.0f, 0.980785280403230f, 0.923879532511287f, 0.831469612302545f,
    0.707106781186548f, 0.555570233019602f, 0.382683432365090f, 0.195090322016128f};

// cos/sin(2*pi*k/64), k=0..32 (recon twiddles e^{-2pi i k/64} = TC - i*TS; Hann source)
constexpr float TC[33] = {
    1.0f, 0.995184726672197f, 0.980785280403230f, 0.956940335732209f,
    0.923879532511287f, 0.881921264348355f, 0.831469612302545f, 0.773010453362737f,
    0.707106781186548f, 0.634393284163645f, 0.555570233019602f, 0.471396736825998f,
    0.382683432365090f, 0.290284677254462f, 0.195090322016128f, 0.098017140329561f,
    0.0f, -0.098017140329561f, -0.195090322016128f, -0.290284677254462f,
    -0.382683432365090f, -0.471396736825998f, -0.555570233019602f, -0.634393284163645f,
    -0.707106781186548f, -0.773010453362737f, -0.831469612302545f, -0.881921264348355f,
    -0.923879532511287f, -0.956940335732209f, -0.980785280403230f, -0.995184726672197f,
    -1.0f};
constexpr float TS[33] = {
    0.0f, 0.098017140329561f, 0.195090322016128f, 0.290284677254462f,
    0.382683432365090f, 0.471396736825998f, 0.555570233019602f, 0.634393284163645f,
    0.707106781186548f, 0.773010453362737f, 0.831469612302545f, 0.881921264348355f,
    0.923879532511287f, 0.956940335732209f, 0.980785280403230f, 0.995184726672197f,
    1.0f, 0.995184726672197f, 0.980785280403230f, 0.956940335732209f,
    0.923879532511287f, 0.881921264348355f, 0.831469612302545f, 0.773010453362737f,
    0.707106781186548f, 0.634393284163645f, 0.555570233019602f, 0.471396736825998f,
    0.382683432365090f, 0.290284677254462f, 0.195090322016128f, 0.098017140329561f};

// 4-bit bit reversal
constexpr int BR16[16] = {0, 8, 4, 12, 2, 10, 6, 14, 1, 9, 5, 13, 3, 11, 7, 15};

// periodic Hann scaled by 0.5 (even/odd extraction factor folded in):
// w[n] = 0.25*(1 - cos(2*pi*n/64)); compile-time n -> literal
__device__ __forceinline__ constexpr float hann_half(int n) {
    return 0.25f * (1.0f - TC[(n <= 32) ? n : (64 - n)]);
}

__global__ __launch_bounds__(BLOCK_THREADS, 4)
void SpectralTokenizer_36103495090536_kernel(const float* __restrict__ in,
                                             float* __restrict__ out,
                                             int nrows) {
    __shared__ float so[ROWS_PER_BLOCK * OUT_PER_ROW];  // 42,240 B -> 3 blocks/CU

    const int tid = threadIdx.x;
    const int h = tid & 1;            // half: lane pairs (2p, 2p+1) share one frame
    const int pair = tid >> 1;        // 320 pairs = 64 rows * 5 frames
    const int row_local = pair / 5;
    const int frame = pair - row_local * 5;
    const long long row = (long long)blockIdx.x * ROWS_PER_BLOCK + row_local;
    const bool active = (row < (long long)nrows);

    // Lane h holds br-slots p = 16h + q (q=0..15) of the packed FFT-32:
    // natural complex index n = 2*br4(q) + h, c_n = (x[2n]*w, x[2n+1]*w).
    float ar[16], ai[16];

    if (active) {
        const float2* src = (const float2*)(in + row * ROW_LEN + frame * 8);
#pragma unroll
        for (int q = 0; q < 16; q++) {
            const int m = BR16[q];
            float2 v = src[2 * m + h];   // floats x[4m+2h], x[4m+2h+1]
            const float wa = h ? hann_half(4 * m + 2) : hann_half(4 * m + 0);
            const float wb = h ? hann_half(4 * m + 3) : hann_half(4 * m + 1);
            ar[q] = v.x * wa;
            ai[q] = v.y * wb;
        }

#define BUTTERFLY(i0, i1, c, sn)                                   \
        {                                                          \
            float tr = (c) * ar[i1] + (sn) * ai[i1];               \
            float ti = (c) * ai[i1] - (sn) * ar[i1];               \
            float ur = ar[i0], ui = ai[i0];                        \
            ar[i0] = ur + tr; ai[i0] = ui + ti;                    \
            ar[i1] = ur - tr; ai[i1] = ui - ti;                    \
        }

        // Stages 1-4 are local to each half (pairs differ in bits 0..3 of p).
        // Stage 1 (hs=1): tw = 1
#pragma unroll
        for (int t = 0; t < 8; t++) BUTTERFLY(2 * t, 2 * t + 1, 1.0f, 0.0f);
        // Stage 2 (hs=2): j=0 -> 1 ; j=1 -> -i
#pragma unroll
        for (int t = 0; t < 4; t++) {
            const int k = 4 * t;
            BUTTERFLY(k + 0, k + 2, 1.0f, 0.0f);
            BUTTERFLY(k + 1, k + 3, 0.0f, 1.0f);
        }
        // Stage 3 (hs=4): tw W^(4j)
#pragma unroll
        for (int t = 0; t < 2; t++) {
            const int k = 8 * t;
            BUTTERFLY(k + 0, k + 4, 1.0f, 0.0f);
            BUTTERFLY(k + 1, k + 5, W32C[4], W32S[4]);
            BUTTERFLY(k + 2, k + 6, 0.0f, 1.0f);
            BUTTERFLY(k + 3, k + 7, W32C[12], W32S[12]);
        }
        // Stage 4 (hs=8): tw W^(2j)
#pragma unroll
        for (int j = 0; j < 8; j++) BUTTERFLY(j, j + 8, W32C[2 * j], W32S[2 * j]);
#undef BUTTERFLY

        // Stage 5 (hs=16, cross-lane): A'[q] = A[q] + W^q*A[16+q] (h=0),
        // A'[16+q] = A[q] - W^q*A[16+q] (h=1). h=1 twiddles its own value,
        // halves swap via shfl_xor, then add/sub.
#pragma unroll
        for (int q = 0; q < 16; q++) {
            const float c = W32C[q], s = W32S[q];
            const float twr = c * ar[q] + s * ai[q];
            const float twi = c * ai[q] - s * ar[q];
            const float sr = h ? twr : ar[q];
            const float si = h ? twi : ai[q];
            const float rr = __shfl_xor(sr, 1);
            const float ri = __shfl_xor(si, 1);
            ar[q] = h ? (rr - twr) : (ar[q] + rr);
            ai[q] = h ? (ri - twi) : (ai[q] + ri);
        }

        // rfft recon (0.5 pre-folded): for output k, with A[km],A[kc],
        // km=k&31, kc=(32-k)&31:
        //   er=Ar[km]+Ar[kc]; ei=Ai[km]-Ai[kc]; pr=Ai[km]+Ai[kc]; pi=Ar[kc]-Ar[km];
        //   x = e + (TC[k] - i*TS[k]) * p ; out = log1p(|x|)
        // h=0 computes k=1..15 (km own q=k, kc = partner q=16-k);
        // h=1 computes k+16    (km own q=k, kc = partner q=16-k).
        // TC[k+16] = -TS[k], TS[k+16] = TC[k] -> operand swaps via selects.
        float* orow = so + row_local * OUT_PER_ROW + frame;
        float* orow2 = orow + 80 * h;   // h=1 writes slots (k+16)*5

        // Specials k=0,32 (h=0, from A[0]) and k=16 (h=1, from A[16]=own q0).
        {
            const float a0r = ar[0], a0i = ai[0];
            const float v0 = __logf(1.0f + fabsf(2.0f * (a0r + a0i)));
            const float v16 = __logf(1.0f + 2.0f * __builtin_amdgcn_sqrtf(
                                  fmaf(a0r, a0r, a0i * a0i)));
            orow2[0] = h ? v16 : v0;                       // k=0 / k=16
            if (!h) orow[160] = __logf(1.0f + fabsf(2.0f * (a0r - a0i)));  // k=32
        }

#pragma unroll
        for (int k = 1; k < 16; k++) {
            const float rr = __shfl_xor(ar[16 - k], 1);   // partner's q=16-k
            const float ri = __shfl_xor(ai[16 - k], 1);
            const float er = ar[k] + rr;
            const float ei = ai[k] - ri;
            const float pr = ai[k] + ri;
            const float pi = rr - ar[k];
            const float npr = -pr;
            const float C = TC[k], S = TS[k];
            const float A1 = h ? pi : pr, B1 = h ? npr : pi;
            const float A2 = h ? npr : pi, B2 = h ? pi : pr;
            const float xr = er + C * A1 + S * B1;
            const float xi = ei + C * A2 - S * B2;
            const float mag = __builtin_amdgcn_sqrtf(fmaf(xr, xr, xi * xi));
            orow2[k * 5] = __logf(1.0f + mag);
        }
    }

    __syncthreads();

    // Block-contiguous coalesced store: 64 rows * 165 floats = 2640 float4s.
    const long long block_base = (long long)blockIdx.x * (ROWS_PER_BLOCK * OUT_PER_ROW);
    const long long total_out = (long long)nrows * OUT_PER_ROW;
    float4* dst = (float4*)(out + block_base);
    const float4* s4 = (const float4*)so;
    for (int t = tid; t < (ROWS_PER_BLOCK * OUT_PER_ROW / 4); t += BLOCK_THREADS) {
        if (block_base + 4 * t + 3 < total_out) dst[t] = s4[t];
    }
}

extern "C" void kernel_launch(void* const* d_in, const int* in_sizes, int n_in,
                              void* d_out, int out_size, void* d_ws, size_t ws_size,
                              hipStream_t stream) {
    const float* in = (const float*)d_in[0];
    float* out = (float*)d_out;
    const int nrows = in_sizes[0] / ROW_LEN;                        // 262144
    const int grid = (nrows + ROWS_PER_BLOCK - 1) / ROWS_PER_BLOCK; // 4096
    hipLaunchKernelGGL(SpectralTokenizer_36103495090536_kernel,
                       dim3(grid), dim3(BLOCK_THREADS), 0, stream, in, out, nrows);
}